// Round 1
// baseline (320.861 us; speedup 1.0000x reference)
//
#include <hip/hip_runtime.h>
#include <hip/hip_bf16.h>

#define NB   4
#define NQL  1024
#define NL   2048
#define NH   16
#define NKVH 4
#define ND   128
#define QSCALE 0.088388347648318447f   // 1/sqrt(128)

typedef __bf16 bf16_t;
typedef __bf16 bf16x4 __attribute__((ext_vector_type(4)));
typedef __bf16 bf16x8 __attribute__((ext_vector_type(8)));
typedef float  f32x4  __attribute__((ext_vector_type(4)));

#define KVBLK    64
#define KSTRIDE  136   // K row stride in bf16 elems (128 + 8 pad) -> 272B, 16B-mult
#define VTSTRIDE 72    // V^T row stride (64 + 8 pad) -> 144B, 16B-mult
#define PSTRIDE  72    // P row stride   (64 + 8 pad) -> 144B, 16B-mult

// ---------------------------------------------------------------------------
// Kernel 1: scatter new k/v tokens into the caches, writing updated caches to
// the output buffers (which the attention kernel then reads).
// ---------------------------------------------------------------------------
__global__ __launch_bounds__(256) void update_cache_kernel(
    const float* __restrict__ knew,
    const float* __restrict__ vnew,
    const float* __restrict__ cache_k,
    const float* __restrict__ cache_v,
    const int*   __restrict__ seq_lens,
    float* __restrict__ new_ck,
    float* __restrict__ new_cv)
{
  const int n4 = NB * NKVH * NL * ND / 4;   // 2^20 float4 per cache
  for (int i = blockIdx.x * blockDim.x + threadIdx.x; i < 2 * n4;
       i += gridDim.x * blockDim.x) {
    const int which = i >= n4;          // 0: k, 1: v
    const int j   = which ? i - n4 : i;
    const int d4  = j & 31;             // float4 column (D/4 = 32)
    const int l   = (j >> 5) & (NL - 1);
    const int kvh = (j >> 16) & (NKVH - 1);
    const int b   = j >> 18;
    const int s   = seq_lens[b];
    float4 val;
    if (l >= s && l < s + NQL) {
      const float* nsrc = which ? vnew : knew;
      val = *(const float4*)(nsrc + (((size_t)(b * NQL + (l - s))) * NKVH + kvh) * ND + d4 * 4);
    } else {
      const float* csrc = which ? cache_v : cache_k;
      val = *(const float4*)(csrc + (((size_t)(b * NKVH + kvh)) * NL + l) * ND + d4 * 4);
    }
    float* dst = which ? new_cv : new_ck;
    *(float4*)(dst + (((size_t)(b * NKVH + kvh)) * NL + l) * ND + d4 * 4) = val;
  }
}

// ---------------------------------------------------------------------------
// Kernel 2: flash attention over the updated cache.
// Block = 256 threads (4 waves). Block owns (b, h, 64 q-rows); wave owns 16.
// ---------------------------------------------------------------------------
__global__ __launch_bounds__(256) void attn_kernel(
    const float* __restrict__ qin,
    const float* __restrict__ ck,
    const float* __restrict__ cv,
    const int*   __restrict__ seq_lens,
    float* __restrict__ out)
{
  __shared__ alignas(16) bf16_t Klds[KVBLK][KSTRIDE];
  __shared__ alignas(16) bf16_t Vtlds[ND][VTSTRIDE];
  __shared__ alignas(16) bf16_t Plds[4][16][PSTRIDE];

  const int tid  = threadIdx.x;
  const int wave = tid >> 6;
  const int lane = tid & 63;
  const int lhi  = lane >> 4;   // 0..3
  const int llo  = lane & 15;   // 0..15

  const int bid = blockIdx.x;               // 1024 blocks
  const int qt  = bid & 15;                 // q-tile (QL/64 = 16)
  const int h   = (bid >> 4) & (NH - 1);
  const int b   = bid >> 8;
  const int kvh = h >> 2;                   // G = 4
  const int s   = seq_lens[b];
  const int q0  = qt * 64;
  const int qw  = q0 + wave * 16;           // wave's q base

  // ---- Q fragments: A-layout row = llo, k = lhi*8 + j (per 32-d chunk) ----
  bf16x8 qf[4];
  {
    const float* qb = qin + ((size_t)((b * NQL + qw + llo) * NH + h)) * ND;
    #pragma unroll
    for (int c = 0; c < 4; ++c) {
      float4 a0 = *(const float4*)(qb + c * 32 + lhi * 8);
      float4 a1 = *(const float4*)(qb + c * 32 + lhi * 8 + 4);
      bf16x8 f;
      f[0] = (bf16_t)(a0.x * QSCALE); f[1] = (bf16_t)(a0.y * QSCALE);
      f[2] = (bf16_t)(a0.z * QSCALE); f[3] = (bf16_t)(a0.w * QSCALE);
      f[4] = (bf16_t)(a1.x * QSCALE); f[5] = (bf16_t)(a1.y * QSCALE);
      f[6] = (bf16_t)(a1.z * QSCALE); f[7] = (bf16_t)(a1.w * QSCALE);
      qf[c] = f;
    }
  }

  f32x4 oacc[8];
  #pragma unroll
  for (int i = 0; i < 8; ++i) oacc[i] = (f32x4){0.f, 0.f, 0.f, 0.f};
  float mrow[4] = {-1e30f, -1e30f, -1e30f, -1e30f};
  float lrow[4] = {0.f, 0.f, 0.f, 0.f};

  const float* kcb = ck + ((size_t)(b * NKVH + kvh)) * NL * ND;
  const float* vcb = cv + ((size_t)(b * NKVH + kvh)) * NL * ND;

  const int lcount = s + q0 + 64;                 // positions needed
  const int ntiles = (lcount + KVBLK - 1) / KVBLK;

  for (int t = 0; t < ntiles; ++t) {
    const int l0 = t * KVBLK;
    __syncthreads();   // all waves done reading previous tile
    // ---- stage K (row-major, padded) and V (transposed, padded) as bf16 ----
    for (int i = tid; i < KVBLK * (ND / 4); i += 256) {
      const int row = i >> 5;
      const int c4  = i & 31;
      const size_t off = (size_t)(l0 + row) * ND + c4 * 4;
      float4 kf4 = *(const float4*)(kcb + off);
      float4 vf4 = *(const float4*)(vcb + off);
      bf16x4 kb;
      kb[0] = (bf16_t)kf4.x; kb[1] = (bf16_t)kf4.y;
      kb[2] = (bf16_t)kf4.z; kb[3] = (bf16_t)kf4.w;
      *(bf16x4*)&Klds[row][c4 * 4] = kb;
      Vtlds[c4 * 4 + 0][row] = (bf16_t)vf4.x;
      Vtlds[c4 * 4 + 1][row] = (bf16_t)vf4.y;
      Vtlds[c4 * 4 + 2][row] = (bf16_t)vf4.z;
      Vtlds[c4 * 4 + 3][row] = (bf16_t)vf4.w;
    }
    __syncthreads();

    // ---- S = Q K^T : 4 col-subtiles x 4 d-chunks of MFMA ----
    f32x4 sacc[4];
    #pragma unroll
    for (int sub = 0; sub < 4; ++sub) {
      f32x4 acc = (f32x4){0.f, 0.f, 0.f, 0.f};
      #pragma unroll
      for (int c = 0; c < 4; ++c) {
        bf16x8 kf = *(const bf16x8*)&Klds[sub * 16 + llo][c * 32 + lhi * 8];
        acc = __builtin_amdgcn_mfma_f32_16x16x32_bf16(qf[c], kf, acc, 0, 0, 0);
      }
      sacc[sub] = acc;
    }

    // ---- mask + online softmax (D-layout: row = lhi*4+r, col = llo) ----
    float tmax[4] = {-1e30f, -1e30f, -1e30f, -1e30f};
    #pragma unroll
    for (int sub = 0; sub < 4; ++sub) {
      const int lcol = l0 + sub * 16 + llo;
      #pragma unroll
      for (int r = 0; r < 4; ++r) {
        float sv = sacc[sub][r];
        if (lcol > s + qw + lhi * 4 + r) sv = -1e30f;
        sacc[sub][r] = sv;
        tmax[r] = fmaxf(tmax[r], sv);
      }
    }
    #pragma unroll
    for (int m = 1; m <= 8; m <<= 1) {
      #pragma unroll
      for (int r = 0; r < 4; ++r)
        tmax[r] = fmaxf(tmax[r], __shfl_xor(tmax[r], m, 64));
    }
    float alpha[4];
    #pragma unroll
    for (int r = 0; r < 4; ++r) {
      const float mnew = fmaxf(mrow[r], tmax[r]);
      alpha[r] = __expf(mrow[r] - mnew);
      mrow[r] = mnew;
    }
    float tsum[4] = {0.f, 0.f, 0.f, 0.f};
    #pragma unroll
    for (int sub = 0; sub < 4; ++sub) {
      #pragma unroll
      for (int r = 0; r < 4; ++r) {
        const float p = __expf(sacc[sub][r] - mrow[r]);
        sacc[sub][r] = p;
        tsum[r] += p;
      }
    }
    #pragma unroll
    for (int m = 1; m <= 8; m <<= 1) {
      #pragma unroll
      for (int r = 0; r < 4; ++r)
        tsum[r] += __shfl_xor(tsum[r], m, 64);
    }
    #pragma unroll
    for (int r = 0; r < 4; ++r)
      lrow[r] = lrow[r] * alpha[r] + tsum[r];
    #pragma unroll
    for (int i = 0; i < 8; ++i) {
      #pragma unroll
      for (int r = 0; r < 4; ++r)
        oacc[i][r] *= alpha[r];
    }

    // ---- P -> per-wave LDS (re-layout to A-fragment), then PV ----
    bf16_t* pw = &Plds[wave][0][0];
    #pragma unroll
    for (int sub = 0; sub < 4; ++sub) {
      #pragma unroll
      for (int r = 0; r < 4; ++r)
        pw[(lhi * 4 + r) * PSTRIDE + sub * 16 + llo] = (bf16_t)sacc[sub][r];
    }
    __asm__ __volatile__("s_waitcnt lgkmcnt(0)" ::: "memory");

    bf16x8 pa[2];
    pa[0] = *(const bf16x8*)&pw[llo * PSTRIDE + lhi * 8];
    pa[1] = *(const bf16x8*)&pw[llo * PSTRIDE + 32 + lhi * 8];
    #pragma unroll
    for (int dt = 0; dt < 8; ++dt) {
      f32x4 acc = oacc[dt];
      #pragma unroll
      for (int ks = 0; ks < 2; ++ks) {
        bf16x8 vb = *(const bf16x8*)&Vtlds[dt * 16 + llo][ks * 32 + lhi * 8];
        acc = __builtin_amdgcn_mfma_f32_16x16x32_bf16(pa[ks], vb, acc, 0, 0, 0);
      }
      oacc[dt] = acc;
    }
  }

  // ---- epilogue: normalize and store ----
  #pragma unroll
  for (int r = 0; r < 4; ++r) lrow[r] = 1.0f / lrow[r];
  #pragma unroll
  for (int dt = 0; dt < 8; ++dt) {
    #pragma unroll
    for (int r = 0; r < 4; ++r) {
      const int qg = qw + lhi * 4 + r;
      out[((size_t)((b * NQL + qg) * NH + h)) * ND + dt * 16 + llo] =
          oacc[dt][r] * lrow[r];
    }
  }
}

// ---------------------------------------------------------------------------
extern "C" void kernel_launch(void* const* d_in, const int* in_sizes, int n_in,
                              void* d_out, int out_size, void* d_ws, size_t ws_size,
                              hipStream_t stream)
{
  const float* q        = (const float*)d_in[0];
  const float* k        = (const float*)d_in[1];
  const float* v        = (const float*)d_in[2];
  const float* cache_k  = (const float*)d_in[3];
  const float* cache_v  = (const float*)d_in[4];
  const int*   seq_lens = (const int*)d_in[5];

  float* out    = (float*)d_out;                       // [B, QL, H*D]
  float* new_ck = out + (size_t)NB * NQL * NH * ND;    // [B, KVH, L, D]
  float* new_cv = new_ck + (size_t)NB * NKVH * NL * ND;

  hipLaunchKernelGGL(update_cache_kernel, dim3(2048), dim3(256), 0, stream,
                     k, v, cache_k, cache_v, seq_lens, new_ck, new_cv);
  hipLaunchKernelGGL(attn_kernel, dim3(NB * NH * (NQL / 64)), dim3(256), 0, stream,
                     q, new_ck, new_cv, seq_lens, out);
}

// Round 2
// 106.740 us; speedup vs baseline: 3.0060x; 3.0060x over previous
//
#include <hip/hip_runtime.h>
#include <hip/hip_bf16.h>
#include <stdint.h>

#define NB 4
#define NQL 1024
#define NL 2048
#define NH 16
#define NKVH 4
#define ND 128
#define KVBLK 64
// (1/sqrt(128)) * log2(e): scores land in log2 domain, softmax uses exp2
#define QSCALE_LOG2E 0.1275174340213733f

typedef __bf16 bf16_t;
typedef __bf16 bf16x4 __attribute__((ext_vector_type(4)));
typedef __bf16 bf16x8 __attribute__((ext_vector_type(8)));
typedef float f32x4 __attribute__((ext_vector_type(4)));
typedef float f32x16 __attribute__((ext_vector_type(16)));
typedef uint32_t u32;
typedef unsigned short u16;

__device__ __forceinline__ void gload_lds16(const void* g, void* l) {
  __builtin_amdgcn_global_load_lds((const __attribute__((address_space(1))) void*)g,
                                   (__attribute__((address_space(3))) void*)l,
                                   16, 0, 0);
}

__device__ __forceinline__ u32 pack_bf16(float a, float b) {
  u32 ua = (u32)__builtin_bit_cast(u16, (bf16_t)a);
  u32 ub = (u32)__builtin_bit_cast(u16, (bf16_t)b);
  return ua | (ub << 16);
}

// ---------------------------------------------------------------------------
// Kernel 1: scatter new k/v into caches -> f32 outputs; also bf16 K copy to ws.
// ---------------------------------------------------------------------------
__global__ __launch_bounds__(256) void update_cache_kernel(
    const float* __restrict__ knew,
    const float* __restrict__ vnew,
    const float* __restrict__ cache_k,
    const float* __restrict__ cache_v,
    const int*   __restrict__ seq_lens,
    float* __restrict__ new_ck,
    float* __restrict__ new_cv,
    bf16_t* __restrict__ kb)
{
  const int n4 = NB * NKVH * NL * ND / 4;
  for (int i = blockIdx.x * blockDim.x + threadIdx.x; i < 2 * n4;
       i += gridDim.x * blockDim.x) {
    const int which = i >= n4;
    const int j   = which ? i - n4 : i;
    const int d4  = j & 31;
    const int l   = (j >> 5) & (NL - 1);
    const int kvh = (j >> 16) & (NKVH - 1);
    const int b   = j >> 18;
    const int s   = seq_lens[b];
    float4 val;
    if (l >= s && l < s + NQL) {
      const float* nsrc = which ? vnew : knew;
      val = *(const float4*)(nsrc + (((size_t)(b * NQL + (l - s))) * NKVH + kvh) * ND + d4 * 4);
    } else {
      const float* csrc = which ? cache_v : cache_k;
      val = *(const float4*)(csrc + (((size_t)(b * NKVH + kvh)) * NL + l) * ND + d4 * 4);
    }
    const size_t coff = (((size_t)(b * NKVH + kvh)) * NL + l) * ND + d4 * 4;
    float* dst = which ? new_cv : new_ck;
    *(float4*)(dst + coff) = val;
    if (!which) {
      bf16x4 kv;
      kv[0] = (bf16_t)val.x; kv[1] = (bf16_t)val.y;
      kv[2] = (bf16_t)val.z; kv[3] = (bf16_t)val.w;
      *(bf16x4*)(kb + coff) = kv;
    }
  }
}

// ---------------------------------------------------------------------------
// Kernel 2: build bf16 V^T [B][KVH][D][L] from updated f32 V cache.
// 512 blocks; each transposes a 64l x 128d panel via padded f32 LDS tile.
// ---------------------------------------------------------------------------
__global__ __launch_bounds__(256) void transpose_v_kernel(
    const float* __restrict__ new_cv, bf16_t* __restrict__ vt)
{
  __shared__ float T[64][129];
  const int tid = threadIdx.x;
  const int bid = blockIdx.x;        // B*KVH*(NL/64) = 512
  const int lt  = bid & 31;
  const int kvh = (bid >> 5) & (NKVH - 1);
  const int b   = bid >> 7;
  const int l0  = lt * 64;

  const float* src = new_cv + (((size_t)(b * NKVH + kvh)) * NL + l0) * ND;
  #pragma unroll
  for (int j = 0; j < 8; ++j) {
    const int i   = tid + j * 256;   // 2048 float4
    const int row = i >> 5, c4 = i & 31;
    float4 v = *(const float4*)(src + row * ND + c4 * 4);
    T[row][c4 * 4 + 0] = v.x; T[row][c4 * 4 + 1] = v.y;
    T[row][c4 * 4 + 2] = v.z; T[row][c4 * 4 + 3] = v.w;
  }
  __syncthreads();
  bf16_t* dst = vt + ((size_t)(b * NKVH + kvh)) * ND * NL;
  #pragma unroll
  for (int j = 0; j < 4; ++j) {
    const int c = tid + j * 256;     // 1024 16B chunks
    const int d = c >> 3, l8 = c & 7;
    bf16x8 o;
    #pragma unroll
    for (int e = 0; e < 8; ++e) o[e] = (bf16_t)T[l8 * 8 + e][d];
    *(bf16x8*)(dst + (size_t)d * NL + l0 + l8 * 8) = o;
  }
}

// ---------------------------------------------------------------------------
// Kernel 3: flash attention. 512 blocks x 4 waves; wave owns 32 q-rows.
// Swapped 32x32 MFMA (S^T = K·Q, O^T = V^T·P^T); XOR-swizzled LDS tiles
// staged via global_load_lds with pre-swizzled source; 2-deep double buffer.
// ---------------------------------------------------------------------------
#define STAGE(buf, tt) do {                                                  \
    const int l0s = (tt) * KVBLK;                                            \
    _Pragma("unroll")                                                        \
    for (int j = 0; j < 4; ++j) {                                            \
      const int ck = tid + j * 256;                                          \
      const int kr = ck >> 4, kc2 = (ck & 15) ^ (kr & 7);                    \
      gload_lds16(kbb + (size_t)(l0s + kr) * ND + kc2 * 8,                   \
                  &Kl[buf][(wave * 64 + j * 256) * 8]);                      \
      const int vr = ck >> 3, vc2 = (ck & 7) ^ (vr & 7);                     \
      gload_lds16(vtb + (size_t)vr * NL + (l0s + vc2 * 8),                   \
                  &Vl[buf][(wave * 64 + j * 256) * 8]);                      \
    }                                                                        \
  } while (0)

__global__ __launch_bounds__(256, 2) void attn_kernel(
    const float* __restrict__ qin, const bf16_t* __restrict__ kb,
    const bf16_t* __restrict__ vt, const int* __restrict__ seq_lens,
    float* __restrict__ out)
{
  __shared__ bf16_t Kl[2][KVBLK * ND];   // 32 KB (XOR-swizzled rows of 256B)
  __shared__ bf16_t Vl[2][ND * KVBLK];   // 32 KB (XOR-swizzled rows of 128B)

  const int tid  = threadIdx.x;
  const int wave = tid >> 6, lane = tid & 63;
  const int l5   = lane & 31;            // q column within wave
  const int hi5  = lane >> 5;

  // load-balancing qt pairing: bid and bid+256 land on the same CU and get
  // q-tiles summing to 7 -> near-constant tile count per CU.
  const int bid  = blockIdx.x;
  const int half = bid >> 8, r = bid & 255;
  const int b    = r >> 6;
  const int h    = (r >> 2) & (NH - 1);
  const int qt   = half ? (7 - ((r & 3) << 1)) : ((r & 3) << 1);
  const int kvh  = h >> 2;
  const int s    = seq_lens[b];
  const int qw   = qt * 128 + wave * 32;
  const int q    = qw + l5;

  const bf16_t* kbb = kb + ((size_t)(b * NKVH + kvh)) * NL * ND;
  const bf16_t* vtb = vt + ((size_t)(b * NKVH + kvh)) * ND * NL;

  // Q fragments (B operand of S^T): qf[kc][j] = Q[q][kc*16 + hi5*8 + j]
  bf16x8 qf[8];
  {
    const float* qb = qin + ((size_t)((b * NQL + q) * NH + h)) * ND;
    #pragma unroll
    for (int kc = 0; kc < 8; ++kc) {
      float4 x0 = *(const float4*)(qb + kc * 16 + hi5 * 8);
      float4 x1 = *(const float4*)(qb + kc * 16 + hi5 * 8 + 4);
      bf16x8 f;
      f[0] = (bf16_t)(x0.x * QSCALE_LOG2E); f[1] = (bf16_t)(x0.y * QSCALE_LOG2E);
      f[2] = (bf16_t)(x0.z * QSCALE_LOG2E); f[3] = (bf16_t)(x0.w * QSCALE_LOG2E);
      f[4] = (bf16_t)(x1.x * QSCALE_LOG2E); f[5] = (bf16_t)(x1.y * QSCALE_LOG2E);
      f[6] = (bf16_t)(x1.z * QSCALE_LOG2E); f[7] = (bf16_t)(x1.w * QSCALE_LOG2E);
      qf[kc] = f;
    }
  }

  f32x16 oacc[4];
  #pragma unroll
  for (int i = 0; i < 4; ++i) oacc[i] = (f32x16)(0.f);
  float mreg = -1e30f, lreg = 0.f;

  const int ntiles = (s + qt * 128 + 128 + KVBLK - 1) / KVBLK;
  int cur = 0;
  STAGE(0, 0);
  __syncthreads();

  for (int t = 0; t < ntiles; ++t) {
    const int l0 = t * KVBLK;
    if (t + 1 < ntiles) STAGE(cur ^ 1, t + 1);

    if (l0 <= s + qw + 31) {           // wave has any unmasked element
      // ---- S^T = K · Q : 2 l-subtiles x 8 k-chunks ----
      f32x16 sacc[2];
      #pragma unroll
      for (int sl = 0; sl < 2; ++sl) {
        f32x16 acc = (f32x16)(0.f);
        const int krow = sl * 32 + l5;
        #pragma unroll
        for (int kc = 0; kc < 8; ++kc) {
          bf16x8 kf = *(const bf16x8*)
              &Kl[cur][krow * ND + (((kc * 2 + hi5) ^ (l5 & 7)) * 8)];
          acc = __builtin_amdgcn_mfma_f32_32x32x16_bf16(kf, qf[kc], acc, 0, 0, 0);
        }
        sacc[sl] = acc;
      }
      // ---- ragged-causal mask ----
      if (l0 + 63 > s + qw) {
        const int lim = s + q - l0;    // max valid local l for this lane's q
        #pragma unroll
        for (int sl = 0; sl < 2; ++sl)
          #pragma unroll
          for (int rr = 0; rr < 16; ++rr) {
            const int ll = sl * 32 + (rr & 3) + 8 * (rr >> 2) + 4 * hi5;
            if (ll > lim) sacc[sl][rr] = -1e30f;
          }
      }
      // ---- online softmax in log2 domain, defer-max (THR=8) ----
      float pmax = sacc[0][0];
      #pragma unroll
      for (int sl = 0; sl < 2; ++sl)
        #pragma unroll
        for (int rr = 0; rr < 16; ++rr) pmax = fmaxf(pmax, sacc[sl][rr]);
      pmax = fmaxf(pmax, __shfl_xor(pmax, 32, 64));
      if (!__all(pmax - mreg <= 8.f)) {
        const float mnew  = fmaxf(mreg, pmax);
        const float alpha = exp2f(mreg - mnew);
        mreg = mnew;
        lreg *= alpha;
        #pragma unroll
        for (int i = 0; i < 4; ++i) oacc[i] *= alpha;
      }
      float tsum = 0.f;
      #pragma unroll
      for (int sl = 0; sl < 2; ++sl)
        #pragma unroll
        for (int rr = 0; rr < 16; ++rr) {
          const float p = exp2f(sacc[sl][rr] - mreg);
          sacc[sl][rr] = p;
          tsum += p;
        }
      lreg += tsum + __shfl_xor(tsum, 32, 64);

      // ---- pack P rows to bf16 4-run groups: pk[sl][m][dword] ----
      u32 pk[2][4][2];
      #pragma unroll
      for (int sl = 0; sl < 2; ++sl)
        #pragma unroll
        for (int m = 0; m < 4; ++m) {
          pk[sl][m][0] = pack_bf16(sacc[sl][m * 4 + 0], sacc[sl][m * 4 + 1]);
          pk[sl][m][1] = pack_bf16(sacc[sl][m * 4 + 2], sacc[sl][m * 4 + 3]);
        }
      // ---- half-swap exchange -> PV B-frags pb[c] (k = c*16 + hi5*8 + j) ----
      bf16x8 pb[4];
      #pragma unroll
      for (int c = 0; c < 4; ++c) {
        const int slp = c >> 1;
        const u32 k0 = hi5 ? pk[slp][(2 * c + 1) & 3][0] : pk[slp][(2 * c) & 3][0];
        const u32 k1 = hi5 ? pk[slp][(2 * c + 1) & 3][1] : pk[slp][(2 * c) & 3][1];
        const u32 s0 = hi5 ? pk[slp][(2 * c) & 3][0] : pk[slp][(2 * c + 1) & 3][0];
        const u32 s1 = hi5 ? pk[slp][(2 * c) & 3][1] : pk[slp][(2 * c + 1) & 3][1];
        const u32 r0 = (u32)__shfl_xor((int)s0, 32, 64);
        const u32 r1 = (u32)__shfl_xor((int)s1, 32, 64);
        union { u32 w[4]; bf16x8 v; } u;
        u.w[0] = hi5 ? r0 : k0;   // j0..3: owner half 0
        u.w[1] = hi5 ? r1 : k1;
        u.w[2] = hi5 ? k0 : r0;   // j4..7: owner half 1
        u.w[3] = hi5 ? k1 : r1;
        pb[c] = u.v;
      }
      // ---- O^T += V^T · P^T : 4 d-subtiles x 4 k-chunks ----
      #pragma unroll
      for (int ds = 0; ds < 4; ++ds) {
        const int vrow = ds * 32 + l5;
        #pragma unroll
        for (int c = 0; c < 4; ++c) {
          bf16x8 va = *(const bf16x8*)
              &Vl[cur][vrow * KVBLK + (((c * 2 + hi5) ^ (l5 & 7)) * 8)];
          oacc[ds] = __builtin_amdgcn_mfma_f32_32x32x16_bf16(va, pb[c], oacc[ds], 0, 0, 0);
        }
      }
    }
    __syncthreads();
    cur ^= 1;
  }

  // ---- epilogue: normalize, store O (d = ds*32 + 8*rq + 4*hi5 + rr) ----
  const float linv = 1.0f / lreg;
  float* ob = out + ((size_t)((b * NQL + q) * NH + h)) * ND;
  #pragma unroll
  for (int ds = 0; ds < 4; ++ds)
    #pragma unroll
    for (int rq = 0; rq < 4; ++rq) {
      float4 v;
      v.x = oacc[ds][rq * 4 + 0] * linv;
      v.y = oacc[ds][rq * 4 + 1] * linv;
      v.z = oacc[ds][rq * 4 + 2] * linv;
      v.w = oacc[ds][rq * 4 + 3] * linv;
      *(float4*)(ob + ds * 32 + rq * 8 + hi5 * 4) = v;
    }
}

// ---------------------------------------------------------------------------
extern "C" void kernel_launch(void* const* d_in, const int* in_sizes, int n_in,
                              void* d_out, int out_size, void* d_ws, size_t ws_size,
                              hipStream_t stream)
{
  const float* q        = (const float*)d_in[0];
  const float* k        = (const float*)d_in[1];
  const float* v        = (const float*)d_in[2];
  const float* cache_k  = (const float*)d_in[3];
  const float* cache_v  = (const float*)d_in[4];
  const int*   seq_lens = (const int*)d_in[5];

  float* out    = (float*)d_out;
  float* new_ck = out + (size_t)NB * NQL * NH * ND;
  float* new_cv = new_ck + (size_t)NB * NKVH * NL * ND;

  bf16_t* kb = (bf16_t*)d_ws;                                 // 8 MB bf16 K
  bf16_t* vt = kb + (size_t)NB * NKVH * NL * ND;              // 8 MB bf16 V^T

  hipLaunchKernelGGL(update_cache_kernel, dim3(2048), dim3(256), 0, stream,
                     k, v, cache_k, cache_v, seq_lens, new_ck, new_cv, kb);
  hipLaunchKernelGGL(transpose_v_kernel, dim3(NB * NKVH * (NL / 64)), dim3(256), 0, stream,
                     new_cv, vt);
  hipLaunchKernelGGL(attn_kernel, dim3(512), dim3(256), 0, stream,
                     q, kb, vt, seq_lens, out);
}